// Round 1
// baseline (147.377 us; speedup 1.0000x reference)
//
#include <hip/hip_runtime.h>

constexpr int kC = 147, kH = 64, kBPM = 32;

typedef __attribute__((ext_vector_type(8)))  short bf16x8;   // MFMA A/B frag
typedef __attribute__((ext_vector_type(4)))  float f32x4;    // 16x16 C/D frag
typedef __attribute__((ext_vector_type(16))) float f32x16;   // 32x32 C/D frag
typedef __attribute__((ext_vector_type(4)))  short s16x4;

__device__ __forceinline__ short f2bf(float f) {             // RNE float->bf16
    unsigned u = __builtin_bit_cast(unsigned, f);
    u += 0x7fffu + ((u >> 16) & 1u);
    return (short)(u >> 16);
}
#define MFMA16(a,b,c) __builtin_amdgcn_mfma_f32_16x16x32_bf16((a),(b),(c),0,0,0)
#define MFMA32(a,b,c) __builtin_amdgcn_mfma_f32_32x32x16_bf16((a),(b),(c),0,0,0)

// Softmax in base 2: Wq and q-bias pre-scaled by 0.25*log2(e); P = 2^s.
#if __has_builtin(__builtin_amdgcn_exp2f)
  #define EXP2(x) __builtin_amdgcn_exp2f(x)
#else
  #define EXP2(x) __expf((x) * 0.6931471805599453f)
#endif
constexpr float kQScale = 0.25f * 1.4426950408889634f;

// LDS strides (shorts); all rows 16B-aligned.
constexpr int QS  = 72;    // X row stride (attn kernel)
constexpr int VSA = 136;   // qkv kernel's half-batch V^T row stride (128 j + pad)
constexpr int PS  = 40;    // per-wave P^T scratch row stride (XOR-swizzled cols)
constexpr int WSS = 168;   // Ws qkv: [c][k], k padded to 160 (XOR-swizzled k)
constexpr int WOS = 72;    // Ws oproj: [n][k], k=64 (XOR-swizzled k)

// Weight staging (512 threads): paired b32 writes, k-groups XOR-swizzled.
__device__ __forceinline__ void stage_w_qkv(const float* __restrict__ W,
                                            float scale, short* Ws, int tid) {
    #pragma unroll
    for (int it = 0; it < 10; ++it) {
        const int i = it * 512 + tid;           // 5120 = 64c x 80 k-pairs
        const int c = i & 63, k = (i >> 6) * 2;
        const float v0 = (k     < kC) ? W[k * kH + c] * scale : 0.f;
        const float v1 = (k + 1 < kC) ? W[(k + 1) * kH + c] * scale : 0.f;
        const unsigned pack = (unsigned)(unsigned short)f2bf(v0)
                            | ((unsigned)(unsigned short)f2bf(v1) << 16);
        *(unsigned*)&Ws[c * WSS + (k ^ (((c >> 3) & 3) << 3))] = pack;
    }
}

// ============================ Kernel A: QKV projection ======================
// 512 blocks = (batch, half-of-128-rows); 512 threads = 8 waves x 16 rows.
// LDS 39.7 KB -> multiple blocks/CU co-resident.
__global__ __launch_bounds__(512, 4) void qkv_kernel(
    const float* __restrict__ pose, const float* __restrict__ bpm_emb,
    const float* __restrict__ Wq, const float* __restrict__ bq,
    const float* __restrict__ Wk, const float* __restrict__ bk,
    const float* __restrict__ Wv, const float* __restrict__ bv,
    const float* __restrict__ Wb, const float* __restrict__ bb,
    short* __restrict__ q_g, short* __restrict__ k_g, short* __restrict__ vT_g)
{
    __shared__ __align__(16) short Ws[64 * WSS];   // 21.5 KB
    __shared__ __align__(16) short vt[64 * VSA];   // 17.4 KB  V^T half: [d][jloc]
    __shared__ float bias_s[192];

    const int tid = threadIdx.x;
    const int w = tid >> 6, lane = tid & 63;
    const int ll = lane & 15, lq = lane >> 4;
    const int b = blockIdx.x >> 1, half = blockIdx.x & 1;
    const size_t pbase = (size_t)b * 256 * kC;
    const int row = half * 128 + w * 16 + ll;      // pose row within batch

    // ---- pose B-frags FIRST (get HBM loads in flight early) ----
    bf16x8 pf[5];
    {
        const float* prow = pose + pbase + (size_t)row * kC;
        #pragma unroll
        for (int ksp = 0; ksp < 5; ++ksp) {
            const int c0 = ksp * 32 + lq * 8;
            float v[8];
            if (c0 + 8 <= kC) {
                const float4 f0 = *(const float4*)(prow + c0);
                const float4 f1 = *(const float4*)(prow + c0 + 4);
                v[0]=f0.x; v[1]=f0.y; v[2]=f0.z; v[3]=f0.w;
                v[4]=f1.x; v[5]=f1.y; v[6]=f1.z; v[7]=f1.w;
            } else {
                #pragma unroll
                for (int e = 0; e < 8; ++e) v[e] = (c0 + e < kC) ? prow[c0 + e] : 0.f;
            }
            bf16x8 t;
            #pragma unroll
            for (int e = 0; e < 8; ++e) t[e] = f2bf(v[e]);
            pf[ksp] = t;
        }
    }
    // ---- combined biases (q-bias pre-scaled by kQScale) ----
    if (tid < 192) {
        const int m = tid >> 6, c = tid & 63;
        float a = ((m == 0) ? bq : (m == 1) ? bk : bv)[c];
        if (m == 1) {
            a += bb[c];
            #pragma unroll
            for (int k2 = 0; k2 < kBPM; ++k2)
                a = fmaf(bpm_emb[b * kBPM + k2], Wb[k2 * kH + c], a);
        }
        if (m == 0) a *= kQScale;
        bias_s[tid] = a;
    }
    stage_w_qkv(Wq, kQScale, Ws, tid);
    __syncthreads();

    // ---- 3 GEMM rounds: q, k -> global bf16; v -> LDS V^T ----
    for (int m = 0; m < 3; ++m) {
        f32x4 acc[4];
        #pragma unroll
        for (int mt = 0; mt < 4; ++mt) acc[mt] = (f32x4){0.f,0.f,0.f,0.f};
        #pragma unroll
        for (int ksp = 0; ksp < 5; ++ksp)
            #pragma unroll
            for (int mt = 0; mt < 4; ++mt) {
                const int c = mt * 16 + ll;
                const int key = ((c >> 3) & 3) << 3;
                const bf16x8 wf = *(const bf16x8*)(Ws + c * WSS + ((ksp*32 + lq*8) ^ key));
                acc[mt] = MFMA16(wf, pf[ksp], acc[mt]);
            }
        __syncthreads();                       // all waves done reading Ws
        if (m == 0)      stage_w_qkv(Wk, 1.0f, Ws, tid);
        else if (m == 1) stage_w_qkv(Wv, 1.0f, Ws, tid);
        // epilogue: D row = out-col mt*16+4lq+r, D col = pose-row
        #pragma unroll
        for (int mt = 0; mt < 4; ++mt) {
            const int c0 = mt * 16 + 4 * lq;
            const float4 bv4 = *(const float4*)&bias_s[m * kH + c0];
            if (m < 2) {
                s16x4 pk;
                pk[0] = f2bf(acc[mt][0] + bv4.x);
                pk[1] = f2bf(acc[mt][1] + bv4.y);
                pk[2] = f2bf(acc[mt][2] + bv4.z);
                pk[3] = f2bf(acc[mt][3] + bv4.w);
                short* dst = (m == 0) ? q_g : k_g;
                *(s16x4*)(dst + ((size_t)b * 256 + row) * kH + c0) = pk;
            } else {                            // V^T into LDS: vt[d][jloc]
                const int jloc = w * 16 + ll;
                vt[(c0 + 0) * VSA + jloc] = f2bf(acc[mt][0] + bv4.x);
                vt[(c0 + 1) * VSA + jloc] = f2bf(acc[mt][1] + bv4.y);
                vt[(c0 + 2) * VSA + jloc] = f2bf(acc[mt][2] + bv4.z);
                vt[(c0 + 3) * VSA + jloc] = f2bf(acc[mt][3] + bv4.w);
            }
        }
        __syncthreads();
    }

    // ---- coalesced dump: LDS V^T half -> global vT[b][d][half*128 + j] ----
    {
        const int d = tid >> 3, j16 = (tid & 7) * 16;   // 64 d x 8 chunks x 16
        const short* src = vt + d * VSA + j16;
        short* dst = vT_g + ((size_t)b * kH + d) * 256 + half * 128 + j16;
        *(int4*)(dst)     = *(const int4*)(src);
        *(int4*)(dst + 8) = *(const int4*)(src + 8);
    }
}

// ===================== Kernel B: attention + out-projection =================
// 512 blocks = (batch, q-half of 128 rows); 512 threads = 8 waves =
// 4 heads x 2 q-groups of 64. q/k/V^T read directly from global (L2-resident).
// LDS 43.5 KB -> 2 blocks/CU resident, 8-wave barrier scope.
__global__ __launch_bounds__(512, 4) void attn_kernel(
    const short* __restrict__ q_g, const short* __restrict__ k_g,
    const short* __restrict__ vT_g,
    const float* __restrict__ Wo, const float* __restrict__ bo,
    float* __restrict__ out)
{
    __shared__ __align__(16) short X[128 * QS];     // 18.4 KB attn-out rows
    __shared__ __align__(16) short WsPt[160 * WOS]; // 23.0 KB: Ws(Wo) ∪ Pt
    __shared__ float l_s[8 * 64];
    short* const Ws = WsPt;
    short* const Pt = WsPt;

    const int tid = threadIdx.x;
    const int w = tid >> 6, lane = tid & 63;
    const int ll = lane & 15, lq = lane >> 4;
    const int lm = lane & 31, lh = lane >> 5;
    const int b = blockIdx.x >> 1, qh = blockIdx.x & 1;
    const int h = w & 3, qsel = w >> 2;
    const int qrow0 = qh * 128 + qsel * 64;          // q rows within batch
    const size_t kvbase = (size_t)b * 256 * kH;

    // ---- q B-frags straight from global ----
    bf16x8 qf[2];
    #pragma unroll
    for (int s32 = 0; s32 < 2; ++s32)
        qf[s32] = *(const bf16x8*)(q_g + kvbase
                    + (size_t)(qrow0 + s32*32 + lm) * kH + h*16 + lh*8);

    f32x4 oacc[2][2];
    #pragma unroll
    for (int s32 = 0; s32 < 2; ++s32) {
        oacc[s32][0] = (f32x4){0.f,0.f,0.f,0.f};
        oacc[s32][1] = (f32x4){0.f,0.f,0.f,0.f};
    }
    float lp[2] = {0.f, 0.f};
    short* Pw = Pt + w * 32 * PS;
    const int wkey = ((lm >> 3) & 3) << 3;           // P write-side XOR key

    #pragma unroll 2
    for (int jb = 0; jb < 8; ++jb) {
        const int j0 = jb * 32;
        const bf16x8 kf = *(const bf16x8*)(k_g + kvbase
                            + (size_t)(j0 + lm) * kH + h*16 + lh*8);
        const bf16x8 vf = *(const bf16x8*)(vT_g
                            + ((size_t)b * kH + h*16 + ll) * 256 + j0 + lq*8);
        #pragma unroll
        for (int s32 = 0; s32 < 2; ++s32) {
            const f32x16 z16 = {0.f,0.f,0.f,0.f,0.f,0.f,0.f,0.f,
                                0.f,0.f,0.f,0.f,0.f,0.f,0.f,0.f};
            const f32x16 s = MFMA32(kf, qf[s32], z16);   // S^T: col=q=lm, row=j
            float sum = 0.f;
            #pragma unroll
            for (int g = 0; g < 4; ++g) {                // j = r + 8g + 4lh
                const float p0 = EXP2(s[4*g + 0]);       // scale folded into Wq
                const float p1 = EXP2(s[4*g + 1]);
                const float p2 = EXP2(s[4*g + 2]);
                const float p3 = EXP2(s[4*g + 3]);
                sum += (p0 + p1) + (p2 + p3);
                s16x4 pk; pk[0] = f2bf(p0); pk[1] = f2bf(p1);
                pk[2] = f2bf(p2); pk[3] = f2bf(p3);
                *(s16x4*)(Pw + lm * PS + ((8*g + 4*lh) ^ wkey)) = pk;
            }
            lp[s32] += sum;
            #pragma unroll
            for (int hf = 0; hf < 2; ++hf) {             // O^T += V^T . P^T
                const int qp = hf * 16 + ll;
                const int rkey = ((qp >> 3) & 3) << 3;
                const bf16x8 pfr = *(const bf16x8*)(Pw + qp * PS + ((lq*8) ^ rkey));
                oacc[s32][hf] = MFMA16(vf, pfr, oacc[s32][hf]);
            }
        }
    }
    #pragma unroll
    for (int s32 = 0; s32 < 2; ++s32) {
        const float l2 = lp[s32] + __shfl_xor(lp[s32], 32);
        if (lane < 32) l_s[w * 64 + s32 * 32 + lm] = l2;
    }
    #pragma unroll
    for (int s32 = 0; s32 < 2; ++s32)
        #pragma unroll
        for (int hf = 0; hf < 2; ++hf) {
            const int qi = s32 * 32 + hf * 16 + ll;
            const float inv = 1.f / l_s[w * 64 + qi];
            s16x4 pk;
            #pragma unroll
            for (int r = 0; r < 4; ++r) pk[r] = f2bf(oacc[s32][hf][r] * inv);
            // X[qsel*64+qi][h*16 + 4lq + r] — wave-private (row,col) tile
            *(s16x4*)(X + (qsel * 64 + qi) * QS + h*16 + 4*lq) = pk;
        }
    __syncthreads();                            // Pt dead, X complete

    // ---- stage Wot[n][k] into Ws (overwrites Pt): paired b32 + swizzle ----
    #pragma unroll
    for (int it = 0; it < 10; ++it) {
        const int i = it * 512 + tid;           // 5120 = 160n x 32 k-pairs
        const int n = i % 160, k = (i / 160) * 2;
        const float v0 = (n < kC) ? Wo[k * kC + n] : 0.f;
        const float v1 = (n < kC) ? Wo[(k + 1) * kC + n] : 0.f;
        const unsigned pack = (unsigned)(unsigned short)f2bf(v0)
                            | ((unsigned)(unsigned short)f2bf(v1) << 16);
        *(unsigned*)&Ws[n * WOS + (k ^ (((n >> 3) & 3) << 3))] = pack;
    }
    __syncthreads();

    // ---- output projection: X[128x64] @ Wo + bo (8 waves x 16 rows) ----
    bf16x8 xf[2];
    #pragma unroll
    for (int k2 = 0; k2 < 2; ++k2)
        xf[k2] = *(const bf16x8*)(X + (w*16 + ll) * QS + k2*32 + lq*8);

    f32x4 po[10];
    #pragma unroll
    for (int mt = 0; mt < 10; ++mt) po[mt] = (f32x4){0.f,0.f,0.f,0.f};
    #pragma unroll
    for (int k2 = 0; k2 < 2; ++k2)
        #pragma unroll
        for (int mt = 0; mt < 10; ++mt) {
            const int n = mt * 16 + ll;
            const int key = ((n >> 3) & 3) << 3;
            const bf16x8 wf = *(const bf16x8*)(Ws + n * WOS + ((k2*32 + lq*8) ^ key));
            po[mt] = MFMA16(wf, xf[k2], po[mt]);
        }
    {
        const int orow_i = qh * 128 + w * 16 + ll;
        float* orow = out + ((size_t)b * 256 + orow_i) * kC;
        #pragma unroll
        for (int mt = 0; mt < 10; ++mt) {
            const int c0 = mt * 16 + 4 * lq;
            if (mt < 9) {
                const float4 bv4 = *(const float4*)(bo + c0);
                float4 o;
                o.x = po[mt][0] + bv4.x; o.y = po[mt][1] + bv4.y;
                o.z = po[mt][2] + bv4.z; o.w = po[mt][3] + bv4.w;
                *(float4*)(orow + c0) = o;
            } else {
                #pragma unroll
                for (int r = 0; r < 4; ++r) {
                    const int c = c0 + r;
                    if (c < kC) orow[c] = po[mt][r] + bo[c];
                }
            }
        }
    }
}

extern "C" void kernel_launch(void* const* d_in, const int* in_sizes, int n_in,
                              void* d_out, int out_size, void* d_ws, size_t ws_size,
                              hipStream_t stream) {
    const float* pose    = (const float*)d_in[0];
    const float* bpm_emb = (const float*)d_in[1];
    const float* Wq = (const float*)d_in[2];  const float* bq = (const float*)d_in[3];
    const float* Wk = (const float*)d_in[4];  const float* bk = (const float*)d_in[5];
    const float* Wv = (const float*)d_in[6];  const float* bv = (const float*)d_in[7];
    const float* Wb = (const float*)d_in[8];  const float* bb = (const float*)d_in[9];
    const float* Wo = (const float*)d_in[10]; const float* bo = (const float*)d_in[11];
    float* out = (float*)d_out;

    // workspace: q, k (row-major [b][t][64]) and V^T ([b][64][t]) in bf16
    short* q_g  = (short*)d_ws;
    short* k_g  = q_g + (size_t)256 * 256 * kH;
    short* vT_g = k_g + (size_t)256 * 256 * kH;

    qkv_kernel<<<512, 512, 0, stream>>>(
        pose, bpm_emb, Wq, bq, Wk, bk, Wv, bv, Wb, bb, q_g, k_g, vT_g);
    attn_kernel<<<512, 512, 0, stream>>>(q_g, k_g, vT_g, Wo, bo, out);
}

// Round 2
// 139.051 us; speedup vs baseline: 1.0599x; 1.0599x over previous
//
#include <hip/hip_runtime.h>

constexpr int kC = 147, kH = 64, kBPM = 32;

typedef __attribute__((ext_vector_type(8)))  short bf16x8;   // MFMA A/B frag
typedef __attribute__((ext_vector_type(4)))  float f32x4;    // 16x16 C/D frag
typedef __attribute__((ext_vector_type(16))) float f32x16;   // 32x32 C/D frag
typedef __attribute__((ext_vector_type(2)))  unsigned u32x2;
typedef __attribute__((ext_vector_type(4)))  unsigned u32x4;

__device__ __forceinline__ short f2bf(float f) {             // RNE float->bf16
    unsigned u = __builtin_bit_cast(unsigned, f);
    u += 0x7fffu + ((u >> 16) & 1u);
    return (short)(u >> 16);
}
// Packed RNE f32x2 -> bf16x2 (single VALU op; bit-identical to f2bf pairs).
__device__ __forceinline__ unsigned cvt_pk(float lo, float hi) {
    unsigned r;
    asm("v_cvt_pk_bf16_f32 %0, %1, %2" : "=v"(r) : "v"(lo), "v"(hi));
    return r;
}
#define MFMA16(a,b,c) __builtin_amdgcn_mfma_f32_16x16x32_bf16((a),(b),(c),0,0,0)
#define MFMA32(a,b,c) __builtin_amdgcn_mfma_f32_32x32x16_bf16((a),(b),(c),0,0,0)

// Softmax in base 2: Wq and q-bias pre-scaled by 0.25*log2(e); P = 2^s.
#if __has_builtin(__builtin_amdgcn_exp2f)
  #define EXP2(x) __builtin_amdgcn_exp2f(x)
#else
  #define EXP2(x) __expf((x) * 0.6931471805599453f)   // exact: e^(x ln2) = 2^x
#endif
constexpr float kQScale = 0.25f * 1.4426950408889634f;

// LDS strides (shorts); all rows 16B-aligned.
constexpr int QS  = 72;    // qs/ks row stride
constexpr int VS  = 264;   // vt row stride
constexpr int PS  = 40;    // per-wave P^T scratch row stride (XOR-swizzled cols)
constexpr int WSS = 168;   // Ws qkv: [c][k], k padded to 160 (XOR-swizzled k)
constexpr int WOS = 72;    // Ws oproj: [n][k], k=64 (XOR-swizzled k)

// Weight staging, conflict-free map: lanes sweep 16 consecutive k-dwords per c
// (4 c-rows/wave at stride 84 dw -> runs interleave, 2-way = free).  XOR key
// on 8-short units matches the read side.
__device__ __forceinline__ void stage_w_qkv(const float* __restrict__ W,
                                            float scale, short* Ws, int tid) {
    #pragma unroll
    for (int it = 0; it < 5; ++it) {
        const int i = it * 1024 + tid;          // 5120 = 64c x 80 k-dwords
        const int c = (i >> 4) & 63;
        const int k = (it * 16 + (i & 15)) * 2; // dword index -> short index
        const float v0 = (k     < kC) ? W[k * kH + c] * scale : 0.f;
        const float v1 = (k + 1 < kC) ? W[(k + 1) * kH + c] * scale : 0.f;
        *(unsigned*)&Ws[c * WSS + (k ^ (((c >> 3) & 3) << 3))] = cvt_pk(v0, v1);
    }
}

// One block per batch: 1024 threads = 16 waves = 4 waves/SIMD; LDS 155.4 KB.
__global__ __launch_bounds__(1024, 4) void fused_kernel(
    const float* __restrict__ pose, const float* __restrict__ bpm_emb,
    const float* __restrict__ Wq, const float* __restrict__ bq,
    const float* __restrict__ Wk, const float* __restrict__ bk,
    const float* __restrict__ Wv, const float* __restrict__ bv,
    const float* __restrict__ Wb, const float* __restrict__ bb,
    const float* __restrict__ Wo, const float* __restrict__ bo,
    float* __restrict__ out)
{
    __shared__ __align__(16) short qs[256 * QS];    // q, later attn-out X  36.9 KB
    __shared__ __align__(16) short ks_[256 * QS];   // k (+bpm bias)        36.9 KB
    __shared__ __align__(16) short vt[kH * VS];     // V^T: [h*16+d][j]     33.8 KB
    __shared__ __align__(16) short Ws0[64 * WSS];   // W dbuf A ∪ P(w<8) ∪ Wo[<144]
    __shared__ __align__(16) short Ws1[64 * WSS];   // W dbuf B ∪ P(w>=8) ∪ Wo[>=144]
    __shared__ float l_s[16 * 64];                  // per-wave row-sums     4.0 KB
    __shared__ float bias_s[192];

    const int tid = threadIdx.x;
    const int w = tid >> 6, lane = tid & 63;
    const int ll = lane & 15, lq = lane >> 4;
    const int lm = lane & 31, lh = lane >> 5;
    const int b = blockIdx.x;
    const size_t pbase = (size_t)b * 256 * kC;

    // ---- pose B-frags FIRST (get HBM loads in flight early) ----
    bf16x8 pf[5];
    {
        const int row = w * 16 + ll;
        const float* prow = pose + pbase + (size_t)row * kC;
        #pragma unroll
        for (int ksp = 0; ksp < 5; ++ksp) {
            const int c0 = ksp * 32 + lq * 8;
            float v[8];
            if (c0 + 8 <= kC) {
                const float4 f0 = *(const float4*)(prow + c0);
                const float4 f1 = *(const float4*)(prow + c0 + 4);
                v[0]=f0.x; v[1]=f0.y; v[2]=f0.z; v[3]=f0.w;
                v[4]=f1.x; v[5]=f1.y; v[6]=f1.z; v[7]=f1.w;
            } else {
                #pragma unroll
                for (int e = 0; e < 8; ++e) v[e] = (c0 + e < kC) ? prow[c0 + e] : 0.f;
            }
            const u32x4 t = { cvt_pk(v[0], v[1]), cvt_pk(v[2], v[3]),
                              cvt_pk(v[4], v[5]), cvt_pk(v[6], v[7]) };
            pf[ksp] = __builtin_bit_cast(bf16x8, t);
        }
    }
    // ---- combined biases (q-bias pre-scaled by kQScale) ----
    if (tid < 192) {
        const int m = tid >> 6, c = tid & 63;
        float a = ((m == 0) ? bq : (m == 1) ? bk : bv)[c];
        if (m == 1) {
            a += bb[c];
            #pragma unroll
            for (int k2 = 0; k2 < kBPM; ++k2)
                a = fmaf(bpm_emb[b * kBPM + k2], Wb[k2 * kH + c], a);
        }
        if (m == 0) a *= kQScale;
        bias_s[tid] = a;
    }
    // ---- stage Wq*kQScale ----
    stage_w_qkv(Wq, kQScale, Ws0, tid);
    __syncthreads();

    // ================= QKV: wave = 16 pose rows, A = W^T (M=64 cols) =======
    // Double-buffered Ws: stage next W concurrently with current MFMAs
    // (separate __shared__ arrays -> no false LDS dependency). 1 barrier/round.
    #pragma unroll
    for (int m = 0; m < 3; ++m) {
        if (m == 0)      stage_w_qkv(Wk, 1.0f, Ws1, tid);
        else if (m == 1) stage_w_qkv(Wv, 1.0f, Ws0, tid);
        const short* R = (m == 1) ? Ws1 : Ws0;
        f32x4 acc[4];
        #pragma unroll
        for (int mt = 0; mt < 4; ++mt) acc[mt] = (f32x4){0.f,0.f,0.f,0.f};
        #pragma unroll
        for (int ksp = 0; ksp < 5; ++ksp)
            #pragma unroll
            for (int mt = 0; mt < 4; ++mt) {
                const int c = mt * 16 + ll;
                const int key = ((c >> 3) & 3) << 3;
                const bf16x8 wf = *(const bf16x8*)(R + c * WSS + ((ksp*32 + lq*8) ^ key));
                acc[mt] = MFMA16(wf, pf[ksp], acc[mt]);
            }
        // epilogue: D row = out-col mt*16+4lq+r, D col = pose-row w*16+ll
        const int row = w * 16 + ll;
        #pragma unroll
        for (int mt = 0; mt < 4; ++mt) {
            const int c0 = mt * 16 + 4 * lq;
            const float4 bv4 = *(const float4*)&bias_s[m * kH + c0];
            if (m < 2) {
                const u32x2 pk = { cvt_pk(acc[mt][0] + bv4.x, acc[mt][1] + bv4.y),
                                   cvt_pk(acc[mt][2] + bv4.z, acc[mt][3] + bv4.w) };
                *(u32x2*)((m == 0 ? qs : ks_) + row * QS + c0) = pk;
            } else {                            // V stored transposed: vt[c][row]
                vt[(c0 + 0) * VS + row] = f2bf(acc[mt][0] + bv4.x);
                vt[(c0 + 1) * VS + row] = f2bf(acc[mt][1] + bv4.y);
                vt[(c0 + 2) * VS + row] = f2bf(acc[mt][2] + bv4.z);
                vt[(c0 + 3) * VS + row] = f2bf(acc[mt][3] + bv4.w);
            }
        }
        __syncthreads();
    }

    // ================= attention: wave = (head, q-quarter of 64) ===========
    const int h = w & 3;
    const int q0 = (w >> 2) * 64;
    bf16x8 qf[2];                              // B-frags (read own q region)
    #pragma unroll
    for (int s32 = 0; s32 < 2; ++s32)
        qf[s32] = *(const bf16x8*)(qs + (q0 + s32*32 + lm) * QS + h*16 + lh*8);

    f32x4 oacc[2][2];
    #pragma unroll
    for (int s32 = 0; s32 < 2; ++s32) {
        oacc[s32][0] = (f32x4){0.f,0.f,0.f,0.f};
        oacc[s32][1] = (f32x4){0.f,0.f,0.f,0.f};
    }
    float lp[2] = {0.f, 0.f};
    // per-wave P scratch: waves 0-7 in Ws0, 8-15 in Ws1 (both dead now)
    short* Pw = (w < 8) ? (Ws0 + w * 32 * PS) : (Ws1 + (w - 8) * 32 * PS);
    const int wkey = ((lm >> 3) & 3) << 3;     // P write-side XOR key (per q'=lm)
    const f32x16 z16 = {0.f,0.f,0.f,0.f,0.f,0.f,0.f,0.f,
                        0.f,0.f,0.f,0.f,0.f,0.f,0.f,0.f};

    #pragma unroll 2
    for (int jb = 0; jb < 8; ++jb) {
        const int j0 = jb * 32;
        const bf16x8 kf = *(const bf16x8*)(ks_ + (j0 + lm) * QS + h*16 + lh*8);
        const bf16x8 vf = *(const bf16x8*)(vt + (h*16 + ll) * VS + j0 + lq*8);

        // ---- s32=0: QK^T, exp, stage P0 ----
        __builtin_amdgcn_s_setprio(1);
        const f32x16 s0 = MFMA32(kf, qf[0], z16);    // S^T: col=q=lm, row=j
        __builtin_amdgcn_s_setprio(0);
        float sum0 = 0.f;
        unsigned u0[8];
        #pragma unroll
        for (int g = 0; g < 4; ++g) {                // j = r + 8g + 4lh
            const float p0 = EXP2(s0[4*g + 0]);      // scale folded into Wq
            const float p1 = EXP2(s0[4*g + 1]);
            const float p2 = EXP2(s0[4*g + 2]);
            const float p3 = EXP2(s0[4*g + 3]);
            sum0 += (p0 + p1) + (p2 + p3);
            u0[2*g]   = cvt_pk(p0, p1);
            u0[2*g+1] = cvt_pk(p2, p3);
        }
        lp[0] += sum0;
        #pragma unroll
        for (int g = 0; g < 4; ++g) {
            const u32x2 pk = { u0[2*g], u0[2*g+1] };
            *(u32x2*)(Pw + lm * PS + ((8*g + 4*lh) ^ wkey)) = pk;
        }

        // ---- s32=1: QK^T + exp held in regs (hides P0 write latency) ----
        __builtin_amdgcn_s_setprio(1);
        const f32x16 s1 = MFMA32(kf, qf[1], z16);
        __builtin_amdgcn_s_setprio(0);
        float sum1 = 0.f;
        unsigned u1[8];
        #pragma unroll
        for (int g = 0; g < 4; ++g) {
            const float p0 = EXP2(s1[4*g + 0]);
            const float p1 = EXP2(s1[4*g + 1]);
            const float p2 = EXP2(s1[4*g + 2]);
            const float p3 = EXP2(s1[4*g + 3]);
            sum1 += (p0 + p1) + (p2 + p3);
            u1[2*g]   = cvt_pk(p0, p1);
            u1[2*g+1] = cvt_pk(p2, p3);
        }
        lp[1] += sum1;

        // ---- PV(0): read P0 (write long since retired), accumulate ----
        __builtin_amdgcn_s_setprio(1);
        #pragma unroll
        for (int hf = 0; hf < 2; ++hf) {             // O^T += V^T . P^T
            const int qp = hf * 16 + ll;
            const int rkey = ((qp >> 3) & 3) << 3;
            const bf16x8 pfr = *(const bf16x8*)(Pw + qp * PS + ((lq*8) ^ rkey));
            oacc[0][hf] = MFMA16(vf, pfr, oacc[0][hf]);
        }
        __builtin_amdgcn_s_setprio(0);

        // ---- stage P1 (in-order DS: lands after the P0 reads above) ----
        #pragma unroll
        for (int g = 0; g < 4; ++g) {
            const u32x2 pk = { u1[2*g], u1[2*g+1] };
            *(u32x2*)(Pw + lm * PS + ((8*g + 4*lh) ^ wkey)) = pk;
        }
        // ---- PV(1) ----
        __builtin_amdgcn_s_setprio(1);
        #pragma unroll
        for (int hf = 0; hf < 2; ++hf) {
            const int qp = hf * 16 + ll;
            const int rkey = ((qp >> 3) & 3) << 3;
            const bf16x8 pfr = *(const bf16x8*)(Pw + qp * PS + ((lq*8) ^ rkey));
            oacc[1][hf] = MFMA16(vf, pfr, oacc[1][hf]);
        }
        __builtin_amdgcn_s_setprio(0);
    }
    #pragma unroll
    for (int s32 = 0; s32 < 2; ++s32) {
        const float l2 = lp[s32] + __shfl_xor(lp[s32], 32);
        if (lane < 32) l_s[w * 64 + s32 * 32 + lm] = l2;
    }
    #pragma unroll
    for (int s32 = 0; s32 < 2; ++s32)
        #pragma unroll
        for (int hf = 0; hf < 2; ++hf) {
            const int qi = s32 * 32 + hf * 16 + ll;
            const float inv = 1.f / l_s[w * 64 + qi];
            // X[q0+qi][h*16 + 4lq + r] — wave-private (row,col) tile
            const u32x2 pk = { cvt_pk(oacc[s32][hf][0] * inv, oacc[s32][hf][1] * inv),
                               cvt_pk(oacc[s32][hf][2] * inv, oacc[s32][hf][3] * inv) };
            *(u32x2*)(qs + (q0 + qi) * QS + h*16 + 4*lq) = pk;
        }
    __syncthreads();                            // P dead, X complete

    // ---- stage Wot[n][k] into Ws0(n<144) / Ws1(n>=144): conflict-free map ----
    #pragma unroll
    for (int it = 0; it < 5; ++it) {
        const int i = it * 1024 + tid;          // 5120 = 160n x 32 k-dwords
        const int n = i >> 5, k = (i & 31) * 2;
        const float v0 = (n < kC) ? Wo[k * kC + n] : 0.f;
        const float v1 = (n < kC) ? Wo[(k + 1) * kC + n] : 0.f;
        short* base = (n < 144) ? (Ws0 + n * WOS) : (Ws1 + (n - 144) * WOS);
        *(unsigned*)&base[k ^ (((n >> 3) & 3) << 3)] = cvt_pk(v0, v1);
    }
    __syncthreads();

    // ================= output projection: X[256x64] @ Wo + bo ==============
    bf16x8 xf[2];
    #pragma unroll
    for (int k2 = 0; k2 < 2; ++k2)
        xf[k2] = *(const bf16x8*)(qs + (w*16 + ll) * QS + k2*32 + lq*8);

    f32x4 po[10];
    #pragma unroll
    for (int mt = 0; mt < 10; ++mt) po[mt] = (f32x4){0.f,0.f,0.f,0.f};
    #pragma unroll
    for (int k2 = 0; k2 < 2; ++k2)
        #pragma unroll
        for (int mt = 0; mt < 10; ++mt) {
            const int n = mt * 16 + ll;
            const int key = ((n >> 3) & 3) << 3;
            const short* base = (mt < 9) ? (Ws0 + n * WOS) : (Ws1 + (n - 144) * WOS);
            const bf16x8 wf = *(const bf16x8*)(base + ((k2*32 + lq*8) ^ key));
            po[mt] = MFMA16(wf, xf[k2], po[mt]);
        }
    {
        const int row = w * 16 + ll;
        float* orow = out + ((size_t)b * 256 + row) * kC;
        #pragma unroll
        for (int mt = 0; mt < 10; ++mt) {
            const int c0 = mt * 16 + 4 * lq;
            if (mt < 9) {
                const float4 bv4 = *(const float4*)(bo + c0);
                float4 o;
                o.x = po[mt][0] + bv4.x; o.y = po[mt][1] + bv4.y;
                o.z = po[mt][2] + bv4.z; o.w = po[mt][3] + bv4.w;
                *(float4*)(orow + c0) = o;
            } else {
                #pragma unroll
                for (int r = 0; r < 4; ++r) {
                    const int c = c0 + r;
                    if (c < kC) orow[c] = po[mt][r] + bo[c];
                }
            }
        }
    }
}

extern "C" void kernel_launch(void* const* d_in, const int* in_sizes, int n_in,
                              void* d_out, int out_size, void* d_ws, size_t ws_size,
                              hipStream_t stream) {
    const float* pose    = (const float*)d_in[0];
    const float* bpm_emb = (const float*)d_in[1];
    const float* Wq = (const float*)d_in[2];  const float* bq = (const float*)d_in[3];
    const float* Wk = (const float*)d_in[4];  const float* bk = (const float*)d_in[5];
    const float* Wv = (const float*)d_in[6];  const float* bv = (const float*)d_in[7];
    const float* Wb = (const float*)d_in[8];  const float* bb = (const float*)d_in[9];
    const float* Wo = (const float*)d_in[10]; const float* bo = (const float*)d_in[11];
    float* out = (float*)d_out;

    fused_kernel<<<256, 1024, 0, stream>>>(
        pose, bpm_emb, Wq, bq, Wk, bk, Wv, bv, Wb, bb, Wo, bo, out);
}

// Round 3
// 129.126 us; speedup vs baseline: 1.1413x; 1.0769x over previous
//
#include <hip/hip_runtime.h>

constexpr int kC = 147, kH = 64, kBPM = 32;

typedef __attribute__((ext_vector_type(8)))  short bf16x8;   // MFMA A/B frag
typedef __attribute__((ext_vector_type(4)))  float f32x4;    // 16x16 C/D frag
typedef __attribute__((ext_vector_type(16))) float f32x16;   // 32x32 C/D frag
typedef __attribute__((ext_vector_type(2)))  unsigned u32x2;
typedef __attribute__((ext_vector_type(4)))  unsigned u32x4;

__device__ __forceinline__ short f2bf(float f) {             // RNE float->bf16
    unsigned u = __builtin_bit_cast(unsigned, f);
    u += 0x7fffu + ((u >> 16) & 1u);
    return (short)(u >> 16);
}
// Packed RNE f32x2 -> bf16x2 (single VALU op; bit-identical to f2bf pairs).
__device__ __forceinline__ unsigned cvt_pk(float lo, float hi) {
    unsigned r;
    asm("v_cvt_pk_bf16_f32 %0, %1, %2" : "=v"(r) : "v"(lo), "v"(hi));
    return r;
}
#define MFMA16(a,b,c) __builtin_amdgcn_mfma_f32_16x16x32_bf16((a),(b),(c),0,0,0)
#define MFMA32(a,b,c) __builtin_amdgcn_mfma_f32_32x32x16_bf16((a),(b),(c),0,0,0)

// Softmax in base 2: Wq and q-bias pre-scaled by 0.25*log2(e); P = 2^s.
#if __has_builtin(__builtin_amdgcn_exp2f)
  #define EXP2(x) __builtin_amdgcn_exp2f(x)
#else
  #define EXP2(x) __expf((x) * 0.6931471805599453f)   // exact: e^(x ln2) = 2^x
#endif
constexpr float kQScale = 0.25f * 1.4426950408889634f;

// LDS strides (shorts); all rows 16B-aligned.
constexpr int QS  = 72;    // qs/ks row stride
constexpr int VS  = 264;   // vt row stride
constexpr int PS  = 40;    // per-wave P^T scratch row stride (XOR-swizzled cols)
constexpr int WSS = 168;   // Ws qkv: [c][k], k padded to 160 (XOR-swizzled k)
constexpr int WOS = 72;    // Ws oproj: [n][k], k=64 (XOR-swizzled k)

// LDS write-out of a prefetched W (values already scaled at load time).
// Thread map matches the coalesced load map: c = i&63, k-pair = i>>6.
__device__ __forceinline__ void stage_w_regs(const float* wr /*10*/,
                                             short* Ws, int tid) {
    #pragma unroll
    for (int it = 0; it < 5; ++it) {
        const int i = it * 1024 + tid;          // 5120 = 64c x 80 k-pairs
        const int c = i & 63, k = (i >> 6) * 2;
        *(unsigned*)&Ws[c * WSS + (k ^ (((c >> 3) & 3) << 3))]
            = cvt_pk(wr[2*it], wr[2*it + 1]);
    }
}

// One block per batch: 1024 threads = 16 waves = 4 waves/SIMD; LDS 153.6 KB.
__global__ __launch_bounds__(1024, 4) void fused_kernel(
    const float* __restrict__ pose, const float* __restrict__ bpm_emb,
    const float* __restrict__ Wq, const float* __restrict__ bq,
    const float* __restrict__ Wk, const float* __restrict__ bk,
    const float* __restrict__ Wv, const float* __restrict__ bv,
    const float* __restrict__ Wb, const float* __restrict__ bb,
    const float* __restrict__ Wo, const float* __restrict__ bo,
    float* __restrict__ out)
{
    __shared__ __align__(16) short qs[256 * QS];    // q, later attn-out X  36.9 KB
    __shared__ __align__(16) short ks_[256 * QS];   // k (+bpm bias)        36.9 KB
    __shared__ __align__(16) short vt[kH * VS];     // V^T: [h*16+d][j]     33.8 KB
    __shared__ __align__(16) short WsPt[20480];     // Ws (11520) ∪ Pt      41.0 KB
    __shared__ float l_s[16 * 64];                  // per-wave row-sums     4.0 KB
    __shared__ float bias_s[192];
    short* const Ws = WsPt;
    short* const Pt = WsPt;

    const int tid = threadIdx.x;
    const int w = tid >> 6, lane = tid & 63;
    const int ll = lane & 15, lq = lane >> 4;
    const int lm = lane & 31, lh = lane >> 5;
    const int b = blockIdx.x;
    const size_t pbase = (size_t)b * 256 * kC;

    // ---- T14 async-stage: ALL qkv weights -> regs in prologue (coalesced).
    // Post-barrier stages become pure LDS writes; L2 latency hides here.
    float wq_r[10], wk_r[10], wv_r[10];
    #pragma unroll
    for (int it = 0; it < 5; ++it) {
        const int i = it * 1024 + tid;
        const int c = i & 63, k = (i >> 6) * 2;
        const bool b0 = k < kC, b1 = k + 1 < kC;
        wq_r[2*it]   = b0 ? Wq[k * kH + c] * kQScale : 0.f;
        wq_r[2*it+1] = b1 ? Wq[(k + 1) * kH + c] * kQScale : 0.f;
        wk_r[2*it]   = b0 ? Wk[k * kH + c] : 0.f;
        wk_r[2*it+1] = b1 ? Wk[(k + 1) * kH + c] : 0.f;
        wv_r[2*it]   = b0 ? Wv[k * kH + c] : 0.f;
        wv_r[2*it+1] = b1 ? Wv[(k + 1) * kH + c] : 0.f;
    }

    // ---- pose B-frags (HBM loads in flight early) ----
    bf16x8 pf[5];
    {
        const int row = w * 16 + ll;
        const float* prow = pose + pbase + (size_t)row * kC;
        #pragma unroll
        for (int ksp = 0; ksp < 5; ++ksp) {
            const int c0 = ksp * 32 + lq * 8;
            float v[8];
            if (c0 + 8 <= kC) {
                const float4 f0 = *(const float4*)(prow + c0);
                const float4 f1 = *(const float4*)(prow + c0 + 4);
                v[0]=f0.x; v[1]=f0.y; v[2]=f0.z; v[3]=f0.w;
                v[4]=f1.x; v[5]=f1.y; v[6]=f1.z; v[7]=f1.w;
            } else {
                #pragma unroll
                for (int e = 0; e < 8; ++e) v[e] = (c0 + e < kC) ? prow[c0 + e] : 0.f;
            }
            const u32x4 t = { cvt_pk(v[0], v[1]), cvt_pk(v[2], v[3]),
                              cvt_pk(v[4], v[5]), cvt_pk(v[6], v[7]) };
            pf[ksp] = __builtin_bit_cast(bf16x8, t);
        }
    }
    // ---- combined biases (q-bias pre-scaled by kQScale) ----
    if (tid < 192) {
        const int m = tid >> 6, c = tid & 63;
        float a = ((m == 0) ? bq : (m == 1) ? bk : bv)[c];
        if (m == 1) {
            a += bb[c];
            #pragma unroll
            for (int k2 = 0; k2 < kBPM; ++k2)
                a = fmaf(bpm_emb[b * kBPM + k2], Wb[k2 * kH + c], a);
        }
        if (m == 0) a *= kQScale;
        bias_s[tid] = a;
    }
    // ---- stage Wq (already scaled in regs) ----
    stage_w_regs(wq_r, Ws, tid);
    __syncthreads();

    // ================= QKV: wave = 16 pose rows, A = W^T (M=64 cols) =======
    #pragma unroll
    for (int m = 0; m < 3; ++m) {
        f32x4 acc[4];
        #pragma unroll
        for (int mt = 0; mt < 4; ++mt) acc[mt] = (f32x4){0.f,0.f,0.f,0.f};
        #pragma unroll
        for (int ksp = 0; ksp < 5; ++ksp)
            #pragma unroll
            for (int mt = 0; mt < 4; ++mt) {
                const int c = mt * 16 + ll;
                const int key = ((c >> 3) & 3) << 3;
                const bf16x8 wf = *(const bf16x8*)(Ws + c * WSS + ((ksp*32 + lq*8) ^ key));
                acc[mt] = MFMA16(wf, pf[ksp], acc[mt]);
            }
        __syncthreads();                       // all waves done reading Ws
        if (m == 0)      stage_w_regs(wk_r, Ws, tid);   // pure LDS writes
        else if (m == 1) stage_w_regs(wv_r, Ws, tid);
        // m==2: Ws aliases Pt — no stage
        // epilogue: D row = out-col mt*16+4lq+r, D col = pose-row w*16+ll
        const int row = w * 16 + ll;
        #pragma unroll
        for (int mt = 0; mt < 4; ++mt) {
            const int c0 = mt * 16 + 4 * lq;
            const float4 bv4 = *(const float4*)&bias_s[m * kH + c0];
            if (m < 2) {
                const u32x2 pk = { cvt_pk(acc[mt][0] + bv4.x, acc[mt][1] + bv4.y),
                                   cvt_pk(acc[mt][2] + bv4.z, acc[mt][3] + bv4.w) };
                *(u32x2*)((m == 0 ? qs : ks_) + row * QS + c0) = pk;
            } else {                            // V stored transposed: vt[c][row]
                vt[(c0 + 0) * VS + row] = f2bf(acc[mt][0] + bv4.x);
                vt[(c0 + 1) * VS + row] = f2bf(acc[mt][1] + bv4.y);
                vt[(c0 + 2) * VS + row] = f2bf(acc[mt][2] + bv4.z);
                vt[(c0 + 3) * VS + row] = f2bf(acc[mt][3] + bv4.w);
            }
        }
        __syncthreads();
    }

    // ================= attention: wave = (head, q-quarter of 64) ===========
    const int h = w & 3;
    const int q0 = (w >> 2) * 64;
    bf16x8 qf[2];                              // B-frags (read own q region)
    #pragma unroll
    for (int s32 = 0; s32 < 2; ++s32)
        qf[s32] = *(const bf16x8*)(qs + (q0 + s32*32 + lm) * QS + h*16 + lh*8);

    // ---- T14: prefetch Wo into regs now; consumed ~2000 cy later ----
    float wo_r[10];
    #pragma unroll
    for (int it = 0; it < 5; ++it) {
        const int i = it * 1024 + tid;          // 5120 = 160n x 32 k-pairs
        const int n = i % 160, k = (i / 160) * 2;
        wo_r[2*it]   = (n < kC) ? Wo[k * kC + n] : 0.f;
        wo_r[2*it+1] = (n < kC) ? Wo[(k + 1) * kC + n] : 0.f;
    }

    f32x4 oacc[2][2];
    #pragma unroll
    for (int s32 = 0; s32 < 2; ++s32) {
        oacc[s32][0] = (f32x4){0.f,0.f,0.f,0.f};
        oacc[s32][1] = (f32x4){0.f,0.f,0.f,0.f};
    }
    float lp[2] = {0.f, 0.f};
    short* Pw = Pt + w * 32 * PS;
    const int wkey = ((lm >> 3) & 3) << 3;     // P write-side XOR key (per q'=lm)

    #pragma unroll 2
    for (int jb = 0; jb < 8; ++jb) {
        const int j0 = jb * 32;
        const bf16x8 kf = *(const bf16x8*)(ks_ + (j0 + lm) * QS + h*16 + lh*8);
        const bf16x8 vf = *(const bf16x8*)(vt + (h*16 + ll) * VS + j0 + lq*8);
        #pragma unroll
        for (int s32 = 0; s32 < 2; ++s32) {
            const f32x16 z16 = {0.f,0.f,0.f,0.f,0.f,0.f,0.f,0.f,
                                0.f,0.f,0.f,0.f,0.f,0.f,0.f,0.f};
            const f32x16 s = MFMA32(kf, qf[s32], z16);   // S^T: col=q=lm, row=j
            float sum = 0.f;
            #pragma unroll
            for (int g = 0; g < 4; ++g) {                // j = r + 8g + 4lh
                const float p0 = EXP2(s[4*g + 0]);       // scale folded into Wq
                const float p1 = EXP2(s[4*g + 1]);
                const float p2 = EXP2(s[4*g + 2]);
                const float p3 = EXP2(s[4*g + 3]);
                sum += (p0 + p1) + (p2 + p3);
                const u32x2 pk = { cvt_pk(p0, p1), cvt_pk(p2, p3) };
                *(u32x2*)(Pw + lm * PS + ((8*g + 4*lh) ^ wkey)) = pk;
            }
            lp[s32] += sum;
            #pragma unroll
            for (int half = 0; half < 2; ++half) {       // O^T += V^T . P^T
                const int qp = half * 16 + ll;
                const int rkey = ((qp >> 3) & 3) << 3;
                const bf16x8 pfr = *(const bf16x8*)(Pw + qp * PS + ((lq*8) ^ rkey));
                oacc[s32][half] = MFMA16(vf, pfr, oacc[s32][half]);
            }
        }
    }
    #pragma unroll
    for (int s32 = 0; s32 < 2; ++s32) {
        const float l2 = lp[s32] + __shfl_xor(lp[s32], 32);
        if (lane < 32) l_s[w * 64 + s32 * 32 + lm] = l2;
    }
    #pragma unroll
    for (int s32 = 0; s32 < 2; ++s32)
        #pragma unroll
        for (int half = 0; half < 2; ++half) {
            const int qi = s32 * 32 + half * 16 + ll;
            const float inv = 1.f / l_s[w * 64 + qi];
            // X[q0+qi][h*16 + 4lq + r] — wave-private (row,col) tile
            const u32x2 pk = { cvt_pk(oacc[s32][half][0] * inv, oacc[s32][half][1] * inv),
                               cvt_pk(oacc[s32][half][2] * inv, oacc[s32][half][3] * inv) };
            *(u32x2*)(qs + (q0 + qi) * QS + h*16 + 4*lq) = pk;
        }
    __syncthreads();                            // Pt dead, X complete

    // ---- stage Wot[n][k] into Ws from regs (overwrites Pt) ----
    #pragma unroll
    for (int it = 0; it < 5; ++it) {
        const int i = it * 1024 + tid;
        const int n = i % 160, k = (i / 160) * 2;
        *(unsigned*)&Ws[n * WOS + (k ^ (((n >> 3) & 3) << 3))]
            = cvt_pk(wo_r[2*it], wo_r[2*it + 1]);
    }
    __syncthreads();

    // ================= output projection: X[256x64] @ Wo + bo ==============
    bf16x8 xf[2];
    #pragma unroll
    for (int k2 = 0; k2 < 2; ++k2)
        xf[k2] = *(const bf16x8*)(qs + (w*16 + ll) * QS + k2*32 + lq*8);

    f32x4 po[10];
    #pragma unroll
    for (int mt = 0; mt < 10; ++mt) po[mt] = (f32x4){0.f,0.f,0.f,0.f};
    #pragma unroll
    for (int k2 = 0; k2 < 2; ++k2)
        #pragma unroll
        for (int mt = 0; mt < 10; ++mt) {
            const int n = mt * 16 + ll;
            const int key = ((n >> 3) & 3) << 3;
            const bf16x8 wf = *(const bf16x8*)(Ws + n * WOS + ((k2*32 + lq*8) ^ key));
            po[mt] = MFMA16(wf, xf[k2], po[mt]);
        }
    {
        const int row = w * 16 + ll;
        float* orow = out + ((size_t)b * 256 + row) * kC;
        #pragma unroll
        for (int mt = 0; mt < 10; ++mt) {
            const int c0 = mt * 16 + 4 * lq;
            if (mt < 9) {
                const float4 bv4 = *(const float4*)(bo + c0);
                float4 o;
                o.x = po[mt][0] + bv4.x; o.y = po[mt][1] + bv4.y;
                o.z = po[mt][2] + bv4.z; o.w = po[mt][3] + bv4.w;
                *(float4*)(orow + c0) = o;
            } else {
                #pragma unroll
                for (int r = 0; r < 4; ++r) {
                    const int c = c0 + r;
                    if (c < kC) orow[c] = po[mt][r] + bo[c];
                }
            }
        }
    }
}

extern "C" void kernel_launch(void* const* d_in, const int* in_sizes, int n_in,
                              void* d_out, int out_size, void* d_ws, size_t ws_size,
                              hipStream_t stream) {
    const float* pose    = (const float*)d_in[0];
    const float* bpm_emb = (const float*)d_in[1];
    const float* Wq = (const float*)d_in[2];  const float* bq = (const float*)d_in[3];
    const float* Wk = (const float*)d_in[4];  const float* bk = (const float*)d_in[5];
    const float* Wv = (const float*)d_in[6];  const float* bv = (const float*)d_in[7];
    const float* Wb = (const float*)d_in[8];  const float* bb = (const float*)d_in[9];
    const float* Wo = (const float*)d_in[10]; const float* bo = (const float*)d_in[11];
    float* out = (float*)d_out;

    fused_kernel<<<256, 1024, 0, stream>>>(
        pose, bpm_emb, Wq, bq, Wk, bk, Wv, bv, Wb, bb, Wo, bo, out);
}